// Round 10
// baseline (31342.883 us; speedup 1.0000x reference)
//
#include <hip/hip_runtime.h>
#include <math.h>

#define NN 4096
#define CBLK 8               // worker blocks (ranks)
#define NPB (NN / CBLK)      // 512 neurons per worker block, 8 waves
#define NWAVE 64             // total worker waves = CBLK*8
#define GRID_SIM 128         // candidate blocks; >=16 on some XCD by pigeonhole
#define SLOT_STRIDE 16       // ulls per 128-B line

typedef unsigned long long ull;

// ws layout (pre-zeroed by one hipMemsetAsync each launch):
//   [0..2047]      election: 8 per-XCD roster counters (stride-16 ull) +
//                  chosen at ull index 128                       (R7-proven)
//   [2048..18431]  lines: (parity*64 + waveId)*16 ulls -- per-WAVE tagged
//                  exchange lines, 128 B each
//   [18432..]      cols / part scratch (float)
#define ELECT_BYTES 2048
#define HDR_BYTES (ELECT_BYTES + 2 * NWAVE * SLOT_STRIDE * 8)   // 18432

// --- XCD-local L2 exchange ops: sc0 only (no sc1 -> stays in this XCD's L2,
// which the election makes shared by ALL workers). Inline volatile asm so the
// compiler can neither hoist the poll nor weaken the store. [R8 lesson: scope
// semantics can't express "physically colocated"; raw cache ops can.]
__device__ __forceinline__ ull ld_l2(const ull* p) {
    ull v;
    asm volatile("global_load_dwordx2 %0, %1, off sc0\n\ts_waitcnt vmcnt(0)"
                 : "=v"(v) : "v"(p) : "memory");
    return v;
}
__device__ __forceinline__ void st_l2(ull* p, ull v) {
    asm volatile("global_store_dwordx2 %0, %1, off sc0"
                 :: "v"(p), "v"(v) : "memory");
}

// ---------------- cols precompute: per-type masked column sums of W ----------
__global__ __launch_bounds__(256) void col_partial_k(
    const float* __restrict__ W, const int* __restrict__ Ty,
    float* __restrict__ part, int chunkRows)
{
    const int j4 = (blockIdx.x * 256 + threadIdx.x) * 4;
    const int c = blockIdx.y;
    const size_t i0 = (size_t)c * (size_t)chunkRows;
    float a[6][4];
#pragma unroll
    for (int t = 0; t < 6; ++t)
#pragma unroll
        for (int r = 0; r < 4; ++r) a[t][r] = 0.f;

#pragma unroll 4
    for (size_t i = i0; i < i0 + (size_t)chunkRows; ++i) {
        const size_t off = i * NN + j4;
        const float4 w = *(const float4*)(W + off);
        const int4 t = *(const int4*)(Ty + off);
        const float wv[4] = { w.x, w.y, w.z, w.w };
        const int tv[4] = { t.x, t.y, t.z, t.w };
#pragma unroll
        for (int r = 0; r < 4; ++r) {
            a[0][r] += (tv[r] == 1) ? wv[r] : 0.f;
            a[1][r] += (tv[r] == 2) ? wv[r] : 0.f;
            a[2][r] += (tv[r] == 3) ? wv[r] : 0.f;
            a[3][r] += (tv[r] == 4) ? wv[r] : 0.f;
            a[4][r] += (tv[r] == 5) ? wv[r] : 0.f;
            a[5][r] += (tv[r] == 6) ? wv[r] : 0.f;
        }
    }
    const size_t base = ((size_t)c * 6) * NN + (size_t)j4;
#pragma unroll
    for (int t = 0; t < 6; ++t)
        *(float4*)(part + base + (size_t)t * NN) =
            make_float4(a[t][0], a[t][1], a[t][2], a[t][3]);
}

__global__ __launch_bounds__(256) void col_reduce_k(
    const float* __restrict__ part, float* __restrict__ cols, int CH)
{
    const int idx = blockIdx.x * 256 + threadIdx.x; // t*NN + j
    float s = 0.f;
    for (int c = 0; c < CH; ++c) s += part[(size_t)c * 6 * NN + idx];
    cols[idx] = s;
}

// ---------------- XCD-colocated sim, barrier-free L2 wave exchange ----------
// Election (R7-proven) puts all 8 worker blocks on ONE XCD. Per step, each of
// the 64 worker waves: shfl-reduces its 64 neurons' coupling terms, folds its
// OWN wave-local correction (no LDS/barrier needed), lane0 publishes
// {tag=k+1, float} to the wave's parity line via sc0 store into the shared
// L2 (+ one agent-scope insurance store); runs gate math; then lane l polls
// line l with sc0 loads until all 64 tags match (ballot), and a shfl_xor
// butterfly gives every lane the bit-identical S. Zero __syncthreads in the
// loop. Parity reuse safe: wave W overwrites its parity-p line for k+2 only
// after passing poll(k+1), which requires every wave's publish(k+1), which
// follows their poll(k) in program order. Stale-L2 lines across launches are
// benign: runs are bit-deterministic, so a tag-matched stale value equals the
// true value; mismatches just re-spin. Fallback: after 128k spins the poll
// switches to agent-scope loads (R6/R7-proven visibility path) -> bounded
// degradation instead of a hang if sc0 semantics surprise us.
__global__ __launch_bounds__(NPB) void hh_sim_xcd(
    const float* __restrict__ Iext, const float* __restrict__ V0,
    const float* __restrict__ m0, const float* __restrict__ h0,
    const float* __restrict__ n0, const float* __restrict__ s0,
    const float* __restrict__ cols, const int* __restrict__ Tp,
    ull* __restrict__ ctrl, float* __restrict__ out)
{
#pragma clang fp contract(off)
    const int tid = threadIdx.x;     // 0..511
    const int wave = tid >> 6;       // 0..7
    const int lane = tid & 63;

    // ---- placement-aware worker election (one-time, device scope; R7) ----
    __shared__ int sRank; __shared__ ull sKey, sChosen;
    if (tid == 0) {
        // HW_REG_XCC_ID = hwreg 20, bits [3:0]  [measured: learn_hip m09]
        const int xid = (int)(__builtin_amdgcn_s_getreg((3 << 11) | 20)) & 7;
        const ull r = atomicAdd(&ctrl[(size_t)xid * SLOT_STRIDE], 1ULL);
        if (r == (ull)(CBLK - 1))
            atomicCAS(&ctrl[128], 0ULL, (ull)(xid + 1));
        ull ch;
        do {
            ch = __hip_atomic_load(&ctrl[128],
                                   __ATOMIC_RELAXED, __HIP_MEMORY_SCOPE_AGENT);
        } while (ch == 0ULL);
        sRank = (int)r; sKey = (ull)(xid + 1); sChosen = ch;
    }
    __syncthreads();
    const int b = sRank;             // worker rank
    if (sKey != sChosen || b >= CBLK) return;   // not a worker

    const int steps = Tp[0] * 100;   // T / DT, DT = 0.01
    const int g = b * 8 + wave;      // global worker-wave id, 0..63
    const int j = g * 64 + lane;     // this thread's neuron
    ull* const lines = (ull*)((char*)ctrl + ELECT_BYTES);

    const float tau[6] = { 2.0f, 5.0f, 10.0f, 100.0f, 50.0f, 30.0f };
    const float sgn[6] = { -1.0f, 1.0f, 1.0f, -1.0f, -1.0f, -1.0f };
    float dec[6], sD[6];
#pragma unroll
    for (int t = 0; t < 6; ++t) { dec[t] = 1.0f - 0.01f / tau[t]; sD[t] = sgn[t]; }

    // ---- per-thread state ----
    float V = V0[j], m = m0[j], h = h0[j], n = n0[j], Ie = Iext[j];
    float q[6];
#pragma unroll
    for (int t = 0; t < 6; ++t)
        q[t] = 0.1f * s0[(size_t)t * NN + j] * cols[(size_t)t * NN + j];

    // ---- wave-local correction constants (butterfly -> all lanes) ----
    float CE1, CE2;
    {
        float b1 = q[1], b2 = q[2];
#pragma unroll
        for (int off = 32; off > 0; off >>= 1) {
            b1 += __shfl_xor(b1, off);
            b2 += __shfl_xor(b2, off);
        }
        CE1 = -70.0f * b1;   // E1 * B1_wave
        CE2 = -90.0f * b2;   // E2 * B2_wave
    }

    ull* const myLine = &lines[(size_t)g * SLOT_STRIDE];          // parity 0
    unsigned spins = 0;

    for (int k = 0; k < steps; ++k) {
        // --- advance decay powers; wave-local coupling partial ---
#pragma unroll
        for (int t = 0; t < 6; ++t) sD[t] *= dec[t];
        float w6 = sD[5] * q[5];
        w6 = fmaf(sD[4], q[4], w6);
        w6 = fmaf(sD[3], q[3], w6);
        w6 = fmaf(sD[2], q[2], w6);
        w6 = fmaf(sD[1], q[1], w6);
        w6 = fmaf(sD[0], q[0], w6);
        float x = w6 * V;
#pragma unroll
        for (int off = 32; off > 0; off >>= 1) x += __shfl_down(x, off);

        const unsigned tag = (unsigned)(k + 1);
        const int par = (k & 1) * NWAVE;

        // --- publish: wave-corrected partial to this wave's parity line ---
        if (lane == 0) {
            const float xp = x - fmaf(sD[1], CE1, sD[2] * CE2);
            const ull packed = ((ull)tag << 32) | (ull)__float_as_uint(xp);
            ull* const lp = myLine + (size_t)par * SLOT_STRIDE;
            st_l2(lp, packed);                       // fast path: shared L2
            __hip_atomic_store(lp, packed,           // insurance: IF$ path
                               __ATOMIC_RELAXED, __HIP_MEMORY_SCOPE_AGENT);
        }

        // --- gate math: V-only, overlaps the publish flight ---
        const float v = V;
        const float a1 = 2.5f - 0.1f * v;
        const float X = __expf(a1);
        const float am = a1 * __builtin_amdgcn_rcpf(X - 1.0f);
        const float bm = 4.0f * __expf(v * (-1.0f / 18.0f));
        const float ah = 0.07f * __expf(v * (-1.0f / 20.0f));
        const float bh = __builtin_amdgcn_rcpf(
            fmaf(1.6487212707001281f, X, 1.0f));   // e^{0.5} X + 1
        const float a5 = 0.1f - 0.01f * v;
        const float an = a5 * __builtin_amdgcn_rcpf(
            fmaf(0.2231301601484298f, X, -1.0f));  // e^{-1.5} X - 1
        const float bn = 0.125f * __expf(v * (-1.0f / 80.0f));
        const float mm = m + 0.01f * (am * (1.0f - m) - bm * m);
        const float hh = h + 0.01f * (ah * (1.0f - h) - bh * h);
        const float nn = n + 0.01f * (an * (1.0f - n) - bn * n);
        m = mm; h = hh; n = nn;
        const float INa = ((120.0f * ((mm * mm) * mm)) * hh) * (v - 50.0f);
        const float n2 = nn * nn;
        const float IK = (36.0f * (n2 * n2)) * (v + 77.0f);
        const float IL = 0.3f * (v + 54.387f);
        const float base = ((Ie - INa) - IK) - IL;

        // --- poll: lane l watches line l; exit when all 64 tags match ---
        ull* const wp = &lines[(size_t)(par + lane) * SLOT_STRIDE];
        ull got;
        for (;;) {
            got = (spins < 131072u)
                      ? ld_l2(wp)
                      : __hip_atomic_load(wp, __ATOMIC_RELAXED,
                                          __HIP_MEMORY_SCOPE_AGENT);
            if (__ballot((unsigned)(got >> 32) == tag) ==
                0xFFFFFFFFFFFFFFFFULL) break;
            ++spins;
        }
        // butterfly sum -> bit-identical S in every lane of every wave
        float val = __uint_as_float((unsigned)got);
#pragma unroll
        for (int off = 32; off > 0; off >>= 1) val += __shfl_xor(val, off);
        const float S = val;

        // --- V update + history write ---
        const float u = V + 0.01f * (base + S);
        // clip then nan_to_num: numpy clip propagates NaN -> 0
        V = (u != u) ? 0.0f : fminf(fmaxf(u, -100.0f), 100.0f);
        out[(size_t)k * NN + j] = V;
    }
}

// ---------------- single-block fallback (tiny workspace) --------------------
__global__ __launch_bounds__(1024) void hh_sim_single(
    const float* __restrict__ Iext, const float* __restrict__ V0,
    const float* __restrict__ m0, const float* __restrict__ h0,
    const float* __restrict__ n0, const float* __restrict__ s0,
    const float* __restrict__ colsg, const int* __restrict__ Tp,
    const float* __restrict__ W, const int* __restrict__ Ty,
    int computeCols, float* __restrict__ out)
{
#pragma clang fp contract(off)
    const int tid = threadIdx.x;
    const int j0 = tid * 4;
    const int steps = Tp[0] * 100;

    const float tau[6] = { 2.0f, 5.0f, 10.0f, 100.0f, 50.0f, 30.0f };
    const float sgn[6] = { -1.0f, 1.0f, 1.0f, -1.0f, -1.0f, -1.0f };
    float dec[6], sD[6];
#pragma unroll
    for (int t = 0; t < 6; ++t) { dec[t] = 1.0f - 0.01f / tau[t]; sD[t] = sgn[t]; }

    float q[6][4];
    if (computeCols) {
        float acc[6][4];
#pragma unroll
        for (int t = 0; t < 6; ++t)
#pragma unroll
            for (int r = 0; r < 4; ++r) acc[t][r] = 0.f;
        for (int i = 0; i < NN; ++i) {
            const size_t rowo = (size_t)i * NN + (size_t)j0;
#pragma unroll
            for (int r = 0; r < 4; ++r) {
                const float w = W[rowo + r];
                const int t = Ty[rowo + r];
                acc[0][r] += (t == 1) ? w : 0.f;
                acc[1][r] += (t == 2) ? w : 0.f;
                acc[2][r] += (t == 3) ? w : 0.f;
                acc[3][r] += (t == 4) ? w : 0.f;
                acc[4][r] += (t == 5) ? w : 0.f;
                acc[5][r] += (t == 6) ? w : 0.f;
            }
        }
#pragma unroll
        for (int t = 0; t < 6; ++t)
#pragma unroll
            for (int r = 0; r < 4; ++r)
                q[t][r] = 0.1f * s0[(size_t)t * NN + j0 + r] * acc[t][r];
    } else {
#pragma unroll
        for (int t = 0; t < 6; ++t)
#pragma unroll
            for (int r = 0; r < 4; ++r)
                q[t][r] = 0.1f * s0[(size_t)t * NN + j0 + r] *
                          colsg[(size_t)t * NN + j0 + r];
    }

    float V[4], m[4], h[4], n[4], Ie[4];
#pragma unroll
    for (int r = 0; r < 4; ++r) {
        V[r] = V0[j0 + r]; m[r] = m0[j0 + r]; h[r] = h0[j0 + r];
        n[r] = n0[j0 + r]; Ie[r] = Iext[j0 + r];
    }

    __shared__ float wsum[2][16];
    __shared__ float Bsh[2];
    {
        float b1 = 0.f, b2 = 0.f;
#pragma unroll
        for (int r = 0; r < 4; ++r) { b1 += q[1][r]; b2 += q[2][r]; }
#pragma unroll
        for (int off = 32; off > 0; off >>= 1) {
            b1 += __shfl_down(b1, off);
            b2 += __shfl_down(b2, off);
        }
        if ((tid & 63) == 0) { wsum[0][tid >> 6] = b1; wsum[1][tid >> 6] = b2; }
        __syncthreads();
        if (tid == 0) {
            float s1 = 0.f, s2 = 0.f;
            for (int w2 = 0; w2 < 16; ++w2) { s1 += wsum[0][w2]; s2 += wsum[1][w2]; }
            Bsh[0] = s1; Bsh[1] = s2;
        }
        __syncthreads();
    }
    const float CE1 = -70.0f * Bsh[0];
    const float CE2 = -90.0f * Bsh[1];
    __syncthreads();

    for (int k = 0; k < steps; ++k) {
#pragma unroll
        for (int t = 0; t < 6; ++t) sD[t] *= dec[t];
        float p = 0.f;
#pragma unroll
        for (int r = 0; r < 4; ++r) {
            float w = sD[5] * q[5][r];
            w = fmaf(sD[4], q[4][r], w);
            w = fmaf(sD[3], q[3][r], w);
            w = fmaf(sD[2], q[2][r], w);
            w = fmaf(sD[1], q[1][r], w);
            w = fmaf(sD[0], q[0][r], w);
            p = fmaf(w, V[r], p);
        }
#pragma unroll
        for (int off = 32; off > 0; off >>= 1) p += __shfl_down(p, off);
        const int par = k & 1;
        if ((tid & 63) == 0) wsum[par][tid >> 6] = p;
        __syncthreads();
        float psum = 0.f;
#pragma unroll
        for (int w2 = 0; w2 < 16; ++w2) psum += wsum[par][w2];
        const float S = psum - fmaf(sD[1], CE1, sD[2] * CE2);

#pragma unroll
        for (int r = 0; r < 4; ++r) {
            const float v = V[r];
            const float Ipre = Ie[r] + S;
            const float a1 = 2.5f - 0.1f * v;
            const float X = __expf(a1);
            const float am = a1 * __builtin_amdgcn_rcpf(X - 1.0f);
            const float bm = 4.0f * __expf(v * (-1.0f / 18.0f));
            const float ah = 0.07f * __expf(v * (-1.0f / 20.0f));
            const float bh = __builtin_amdgcn_rcpf(fmaf(1.6487212707001281f, X, 1.0f));
            const float a5 = 0.1f - 0.01f * v;
            const float an = a5 * __builtin_amdgcn_rcpf(fmaf(0.2231301601484298f, X, -1.0f));
            const float bn = 0.125f * __expf(v * (-1.0f / 80.0f));
            const float mm = m[r] + 0.01f * (am * (1.0f - m[r]) - bm * m[r]);
            const float hh = h[r] + 0.01f * (ah * (1.0f - h[r]) - bh * h[r]);
            const float nn = n[r] + 0.01f * (an * (1.0f - n[r]) - bn * n[r]);
            m[r] = mm; h[r] = hh; n[r] = nn;
            const float INa = ((120.0f * ((mm * mm) * mm)) * hh) * (v - 50.0f);
            const float n2 = nn * nn;
            const float IK = (36.0f * (n2 * n2)) * (v + 77.0f);
            const float IL = 0.3f * (v + 54.387f);
            const float u = v + 0.01f * (((Ipre - INa) - IK) - IL);
            V[r] = (u != u) ? 0.0f : fminf(fmaxf(u, -100.0f), 100.0f);
        }
        *(float4*)(out + (size_t)k * NN + j0) =
            make_float4(V[0], V[1], V[2], V[3]);
    }
}

extern "C" void kernel_launch(void* const* d_in, const int* in_sizes, int n_in,
                              void* d_out, int out_size, void* d_ws, size_t ws_size,
                              hipStream_t stream)
{
    const float* Iext = (const float*)d_in[0];
    const float* W    = (const float*)d_in[1];
    const float* V0   = (const float*)d_in[2];
    const float* m0   = (const float*)d_in[3];
    const float* h0   = (const float*)d_in[4];
    const float* n0   = (const float*)d_in[5];
    const float* s0   = (const float*)d_in[6];
    const int*   Ty   = (const int*)d_in[7];
    const int*   Tp   = (const int*)d_in[8];
    float* out = (float*)d_out;

    // ws layout: [election 2048 B][lines 16384 B][cols 6*NN f32][part ...]
    ull*   ctrl = (ull*)d_ws;
    float* cols = (float*)((char*)d_ws + HDR_BYTES);
    float* part = cols + (size_t)6 * NN;

    int CH = 0;
    const int tiers[3] = { 128, 64, 8 };
    for (int i = 0; i < 3; ++i) {
        const size_t need = (size_t)HDR_BYTES + (size_t)(tiers[i] * 6 + 6) * NN * sizeof(float);
        if (ws_size >= need) { CH = tiers[i]; break; }
    }
    if (CH == 0 && ws_size >= (size_t)HDR_BYTES + (size_t)6 * NN * sizeof(float)) CH = 1;

    if (CH >= 1) {
        hipMemsetAsync(ctrl, 0, HDR_BYTES, stream);   // zero election + lines
        if (CH > 1) {
            hipLaunchKernelGGL(col_partial_k, dim3(NN / 1024, CH), dim3(256), 0, stream,
                               W, Ty, part, NN / CH);
            hipLaunchKernelGGL(col_reduce_k, dim3(6 * NN / 256), dim3(256), 0, stream,
                               part, cols, CH);
        } else {
            hipLaunchKernelGGL(col_partial_k, dim3(NN / 1024, 1), dim3(256), 0, stream,
                               W, Ty, cols, NN);
        }
        hipLaunchKernelGGL(hh_sim_xcd, dim3(GRID_SIM), dim3(NPB), 0, stream,
                           Iext, V0, m0, h0, n0, s0, cols, Tp, ctrl, out);
    } else {
        // pathological tiny workspace: single-block kernel computes cols itself
        hipLaunchKernelGGL(hh_sim_single, dim3(1), dim3(1024), 0, stream,
                           Iext, V0, m0, h0, n0, s0, (const float*)0, Tp, W, Ty, 1, out);
    }
}

// Round 11
// 1310.788 us; speedup vs baseline: 23.9115x; 23.9115x over previous
//
#include <hip/hip_runtime.h>
#include <math.h>

#define NN 4096
#define CBLK 8               // worker blocks (ranks)
#define NPB (NN / CBLK)      // 512 neurons per worker block, 8 waves
#define GRID_SIM 128         // candidate blocks; >=16 on some XCD by pigeonhole
#define SLOT_STRIDE 16       // ulls per line: 128 B

typedef unsigned long long ull;

// ctrl layout (ull indices), pre-zeroed by hipMemsetAsync each launch:
//   [0..127]   roster: 8 per-XCD counters at stride 16 (own line each)
//   [128]      chosen: 0 = undecided, else xcd+1
//   [144..399] slots: (parity*8 + rank)*16  -- tag+parity exchange lines
#define CTRL_BYTES 4096

// ---------------- cols precompute: per-type masked column sums of W ----------
// 64-thread single-wave blocks, 4 cols x chunkRows each; 2048 blocks at
// CH=128 -> 8 blocks/CU streaming W+Ty (128 MB) near the BW ceiling.
__global__ __launch_bounds__(64) void col_partial_k(
    const float* __restrict__ W, const int* __restrict__ Ty,
    float* __restrict__ part, int chunkRows)
{
    const int j4 = (blockIdx.x * 64 + threadIdx.x) * 4;
    const int c = blockIdx.y;
    const size_t i0 = (size_t)c * (size_t)chunkRows;
    float a[6][4];
#pragma unroll
    for (int t = 0; t < 6; ++t)
#pragma unroll
        for (int r = 0; r < 4; ++r) a[t][r] = 0.f;

#pragma unroll 4
    for (size_t i = i0; i < i0 + (size_t)chunkRows; ++i) {
        const size_t off = i * NN + j4;
        const float4 w = *(const float4*)(W + off);
        const int4 t = *(const int4*)(Ty + off);
        const float wv[4] = { w.x, w.y, w.z, w.w };
        const int tv[4] = { t.x, t.y, t.z, t.w };
#pragma unroll
        for (int r = 0; r < 4; ++r) {
            a[0][r] += (tv[r] == 1) ? wv[r] : 0.f;
            a[1][r] += (tv[r] == 2) ? wv[r] : 0.f;
            a[2][r] += (tv[r] == 3) ? wv[r] : 0.f;
            a[3][r] += (tv[r] == 4) ? wv[r] : 0.f;
            a[4][r] += (tv[r] == 5) ? wv[r] : 0.f;
            a[5][r] += (tv[r] == 6) ? wv[r] : 0.f;
        }
    }
    const size_t base = ((size_t)c * 6) * NN + (size_t)j4;
#pragma unroll
    for (int t = 0; t < 6; ++t)
        *(float4*)(part + base + (size_t)t * NN) =
            make_float4(a[t][0], a[t][1], a[t][2], a[t][3]);
}

__global__ __launch_bounds__(256) void col_reduce_k(
    const float* __restrict__ part, float* __restrict__ cols, int CH)
{
    const int idx = blockIdx.x * 256 + threadIdx.x; // t*NN + j
    float s = 0.f;
    for (int c = 0; c < CH; ++c) s += part[(size_t)c * 6 * NN + idx];
    cols[idx] = s;
}

// ---------------- XCD-colocated multi-CU simulation (R7 champion) -----------
// 128 candidate blocks; the first 8 to register on the busiest XCD become the
// workers (rank = registration order), everyone else exits. Cross-block
// exchange stays inside ONE XCD (R7-measured: 1.16 us/step vs 1.45 us
// scattered). Per step: 1 barrier; wave0 publishes the block's corrected
// partial as {tag=k+1, float} to its own 128-B line (agent-scope store);
// every wave runs gate math (V-only) under the exchange, then polls all 8
// lines itself (lanes 0..7, agent-scope loads) and shfl-reduces S in-register.
// Parity double-buffer + tag make slot reuse safe (see R5 happens-before
// chain). Session-measured: agent-scope visibility hop ~0.9-1.0 us is the
// structural floor; sub-agent scopes are invalid (R8 hang, R10 31 ms).
__global__ __launch_bounds__(NPB) void hh_sim_xcd(
    const float* __restrict__ Iext, const float* __restrict__ V0,
    const float* __restrict__ m0, const float* __restrict__ h0,
    const float* __restrict__ n0, const float* __restrict__ s0,
    const float* __restrict__ cols, const int* __restrict__ Tp,
    ull* __restrict__ ctrl, float* __restrict__ out)
{
#pragma clang fp contract(off)
    const int tid = threadIdx.x;     // 0..511
    const int wave = tid >> 6;       // 0..7
    const int lane = tid & 63;

    // ---- placement-aware worker election (one-time, device scope) ----
    __shared__ int sRank; __shared__ ull sKey, sChosen;
    if (tid == 0) {
        // HW_REG_XCC_ID = hwreg 20, bits [3:0]  [measured: learn_hip m09]
        const int xid = (int)(__builtin_amdgcn_s_getreg((3 << 11) | 20)) & 7;
        const ull r = atomicAdd(&ctrl[(size_t)xid * SLOT_STRIDE], 1ULL);
        if (r == (ull)(CBLK - 1))
            atomicCAS(&ctrl[128], 0ULL, (ull)(xid + 1));
        ull ch;
        do {
            ch = __hip_atomic_load(&ctrl[128],
                                   __ATOMIC_RELAXED, __HIP_MEMORY_SCOPE_AGENT);
        } while (ch == 0ULL);
        sRank = (int)r; sKey = (ull)(xid + 1); sChosen = ch;
    }
    __syncthreads();
    const int b = sRank;             // worker rank = block id in the protocol
    if (sKey != sChosen || b >= CBLK) return;   // not a worker

    const int steps = Tp[0] * 100;   // T / DT, DT = 0.01
    const int j = b * NPB + tid;     // this thread's neuron
    ull* const slots = ctrl + 144;

    const float tau[6] = { 2.0f, 5.0f, 10.0f, 100.0f, 50.0f, 30.0f };
    const float sgn[6] = { -1.0f, 1.0f, 1.0f, -1.0f, -1.0f, -1.0f };
    float dec[6], sD[6];
#pragma unroll
    for (int t = 0; t < 6; ++t) { dec[t] = 1.0f - 0.01f / tau[t]; sD[t] = sgn[t]; }

    __shared__ float wpart[8];
    __shared__ float binit1[8], binit2[8];

    // ---- per-thread state ----
    float V = V0[j], m = m0[j], h = h0[j], n = n0[j], Ie = Iext[j];
    float q[6];
#pragma unroll
    for (int t = 0; t < 6; ++t)
        q[t] = 0.1f * s0[(size_t)t * NN + j] * cols[(size_t)t * NN + j];

    // ---- block-local correction constants (kept by wave0 lane0) ----
    {
        float b1 = q[1], b2 = q[2];
#pragma unroll
        for (int off = 32; off > 0; off >>= 1) {
            b1 += __shfl_down(b1, off);
            b2 += __shfl_down(b2, off);
        }
        if (lane == 0) { binit1[wave] = b1; binit2[wave] = b2; }
    }
    __syncthreads();
    float CE1 = 0.f, CE2 = 0.f;
    if (wave == 0 && lane == 0) {
        float s1 = 0.f, s2 = 0.f;
#pragma unroll
        for (int w2 = 0; w2 < 8; ++w2) { s1 += binit1[w2]; s2 += binit2[w2]; }
        CE1 = -70.0f * s1;   // E1 * B1_block
        CE2 = -90.0f * s2;   // E2 * B2_block
    }
    __syncthreads();

    for (int k = 0; k < steps; ++k) {
        // --- advance decay powers; wave-local coupling partial ---
#pragma unroll
        for (int t = 0; t < 6; ++t) sD[t] *= dec[t];
        float w6 = sD[5] * q[5];
        w6 = fmaf(sD[4], q[4], w6);
        w6 = fmaf(sD[3], q[3], w6);
        w6 = fmaf(sD[2], q[2], w6);
        w6 = fmaf(sD[1], q[1], w6);
        w6 = fmaf(sD[0], q[0], w6);
        float x = w6 * V;
#pragma unroll
        for (int off = 32; off > 0; off >>= 1) x += __shfl_down(x, off);
        if (lane == 0) wpart[wave] = x;
        __syncthreads();   // the ONLY barrier per step

        const unsigned tag = (unsigned)(k + 1);
        const int par = (k & 1) * CBLK;

        // --- wave0: block sum + publish to this block's own 128-B line ---
        if (wave == 0) {
            float p = (lane < 8) ? wpart[lane] : 0.f;
            p += __shfl_down(p, 4);
            p += __shfl_down(p, 2);
            p += __shfl_down(p, 1);
            if (lane == 0) {
                p = p - fmaf(sD[1], CE1, sD[2] * CE2);
                const ull packed = ((ull)tag << 32) | (ull)__float_as_uint(p);
                __hip_atomic_store(&slots[(size_t)(par + b) * SLOT_STRIDE], packed,
                                   __ATOMIC_RELAXED, __HIP_MEMORY_SCOPE_AGENT);
            }
        }

        // --- gate math: V-only, overlaps the exchange latency ---
        const float v = V;
        const float a1 = 2.5f - 0.1f * v;
        const float X = __expf(a1);
        const float am = a1 * __builtin_amdgcn_rcpf(X - 1.0f);
        const float bm = 4.0f * __expf(v * (-1.0f / 18.0f));
        const float ah = 0.07f * __expf(v * (-1.0f / 20.0f));
        const float bh = __builtin_amdgcn_rcpf(
            fmaf(1.6487212707001281f, X, 1.0f));   // e^{0.5} X + 1
        const float a5 = 0.1f - 0.01f * v;
        const float an = a5 * __builtin_amdgcn_rcpf(
            fmaf(0.2231301601484298f, X, -1.0f));  // e^{-1.5} X - 1
        const float bn = 0.125f * __expf(v * (-1.0f / 80.0f));
        const float mm = m + 0.01f * (am * (1.0f - m) - bm * m);
        const float hh = h + 0.01f * (ah * (1.0f - h) - bh * h);
        const float nn = n + 0.01f * (an * (1.0f - n) - bn * n);
        m = mm; h = hh; n = nn;
        const float INa = ((120.0f * ((mm * mm) * mm)) * hh) * (v - 50.0f);
        const float n2 = nn * nn;
        const float IK = (36.0f * (n2 * n2)) * (v + 77.0f);
        const float IL = 0.3f * (v + 54.387f);
        const float base = ((Ie - INa) - IK) - IL;

        // --- every wave polls the 8 lines itself; reduce in-register ---
        ull got = 0;
        if (lane < 8) {
            do {
                got = __hip_atomic_load(&slots[(size_t)(par + lane) * SLOT_STRIDE],
                                        __ATOMIC_RELAXED, __HIP_MEMORY_SCOPE_AGENT);
            } while ((unsigned)(got >> 32) != tag);
        }
        float val = (lane < 8) ? __uint_as_float((unsigned)got) : 0.f;
        val += __shfl_down(val, 4);
        val += __shfl_down(val, 2);
        val += __shfl_down(val, 1);
        const float S = __shfl(val, 0);

        // --- V update + history write ---
        const float u = V + 0.01f * (base + S);
        // clip then nan_to_num: numpy clip propagates NaN -> 0
        V = (u != u) ? 0.0f : fminf(fmaxf(u, -100.0f), 100.0f);
        out[(size_t)k * NN + j] = V;
    }
}

// ---------------- single-block fallback (tiny workspace) --------------------
__global__ __launch_bounds__(1024) void hh_sim_single(
    const float* __restrict__ Iext, const float* __restrict__ V0,
    const float* __restrict__ m0, const float* __restrict__ h0,
    const float* __restrict__ n0, const float* __restrict__ s0,
    const float* __restrict__ colsg, const int* __restrict__ Tp,
    const float* __restrict__ W, const int* __restrict__ Ty,
    int computeCols, float* __restrict__ out)
{
#pragma clang fp contract(off)
    const int tid = threadIdx.x;
    const int j0 = tid * 4;
    const int steps = Tp[0] * 100;

    const float tau[6] = { 2.0f, 5.0f, 10.0f, 100.0f, 50.0f, 30.0f };
    const float sgn[6] = { -1.0f, 1.0f, 1.0f, -1.0f, -1.0f, -1.0f };
    float dec[6], sD[6];
#pragma unroll
    for (int t = 0; t < 6; ++t) { dec[t] = 1.0f - 0.01f / tau[t]; sD[t] = sgn[t]; }

    float q[6][4];
    if (computeCols) {
        float acc[6][4];
#pragma unroll
        for (int t = 0; t < 6; ++t)
#pragma unroll
            for (int r = 0; r < 4; ++r) acc[t][r] = 0.f;
        for (int i = 0; i < NN; ++i) {
            const size_t rowo = (size_t)i * NN + (size_t)j0;
#pragma unroll
            for (int r = 0; r < 4; ++r) {
                const float w = W[rowo + r];
                const int t = Ty[rowo + r];
                acc[0][r] += (t == 1) ? w : 0.f;
                acc[1][r] += (t == 2) ? w : 0.f;
                acc[2][r] += (t == 3) ? w : 0.f;
                acc[3][r] += (t == 4) ? w : 0.f;
                acc[4][r] += (t == 5) ? w : 0.f;
                acc[5][r] += (t == 6) ? w : 0.f;
            }
        }
#pragma unroll
        for (int t = 0; t < 6; ++t)
#pragma unroll
            for (int r = 0; r < 4; ++r)
                q[t][r] = 0.1f * s0[(size_t)t * NN + j0 + r] * acc[t][r];
    } else {
#pragma unroll
        for (int t = 0; t < 6; ++t)
#pragma unroll
            for (int r = 0; r < 4; ++r)
                q[t][r] = 0.1f * s0[(size_t)t * NN + j0 + r] *
                          colsg[(size_t)t * NN + j0 + r];
    }

    float V[4], m[4], h[4], n[4], Ie[4];
#pragma unroll
    for (int r = 0; r < 4; ++r) {
        V[r] = V0[j0 + r]; m[r] = m0[j0 + r]; h[r] = h0[j0 + r];
        n[r] = n0[j0 + r]; Ie[r] = Iext[j0 + r];
    }

    __shared__ float wsum[2][16];
    __shared__ float Bsh[2];
    {
        float b1 = 0.f, b2 = 0.f;
#pragma unroll
        for (int r = 0; r < 4; ++r) { b1 += q[1][r]; b2 += q[2][r]; }
#pragma unroll
        for (int off = 32; off > 0; off >>= 1) {
            b1 += __shfl_down(b1, off);
            b2 += __shfl_down(b2, off);
        }
        if ((tid & 63) == 0) { wsum[0][tid >> 6] = b1; wsum[1][tid >> 6] = b2; }
        __syncthreads();
        if (tid == 0) {
            float s1 = 0.f, s2 = 0.f;
            for (int w2 = 0; w2 < 16; ++w2) { s1 += wsum[0][w2]; s2 += wsum[1][w2]; }
            Bsh[0] = s1; Bsh[1] = s2;
        }
        __syncthreads();
    }
    const float CE1 = -70.0f * Bsh[0];
    const float CE2 = -90.0f * Bsh[1];
    __syncthreads();

    for (int k = 0; k < steps; ++k) {
#pragma unroll
        for (int t = 0; t < 6; ++t) sD[t] *= dec[t];
        float p = 0.f;
#pragma unroll
        for (int r = 0; r < 4; ++r) {
            float w = sD[5] * q[5][r];
            w = fmaf(sD[4], q[4][r], w);
            w = fmaf(sD[3], q[3][r], w);
            w = fmaf(sD[2], q[2][r], w);
            w = fmaf(sD[1], q[1][r], w);
            w = fmaf(sD[0], q[0][r], w);
            p = fmaf(w, V[r], p);
        }
#pragma unroll
        for (int off = 32; off > 0; off >>= 1) p += __shfl_down(p, off);
        const int par = k & 1;
        if ((tid & 63) == 0) wsum[par][tid >> 6] = p;
        __syncthreads();
        float psum = 0.f;
#pragma unroll
        for (int w2 = 0; w2 < 16; ++w2) psum += wsum[par][w2];
        const float S = psum - fmaf(sD[1], CE1, sD[2] * CE2);

#pragma unroll
        for (int r = 0; r < 4; ++r) {
            const float v = V[r];
            const float Ipre = Ie[r] + S;
            const float a1 = 2.5f - 0.1f * v;
            const float X = __expf(a1);
            const float am = a1 * __builtin_amdgcn_rcpf(X - 1.0f);
            const float bm = 4.0f * __expf(v * (-1.0f / 18.0f));
            const float ah = 0.07f * __expf(v * (-1.0f / 20.0f));
            const float bh = __builtin_amdgcn_rcpf(fmaf(1.6487212707001281f, X, 1.0f));
            const float a5 = 0.1f - 0.01f * v;
            const float an = a5 * __builtin_amdgcn_rcpf(fmaf(0.2231301601484298f, X, -1.0f));
            const float bn = 0.125f * __expf(v * (-1.0f / 80.0f));
            const float mm = m[r] + 0.01f * (am * (1.0f - m[r]) - bm * m[r]);
            const float hh = h[r] + 0.01f * (ah * (1.0f - h[r]) - bh * h[r]);
            const float nn = n[r] + 0.01f * (an * (1.0f - n[r]) - bn * n[r]);
            m[r] = mm; h[r] = hh; n[r] = nn;
            const float INa = ((120.0f * ((mm * mm) * mm)) * hh) * (v - 50.0f);
            const float n2 = nn * nn;
            const float IK = (36.0f * (n2 * n2)) * (v + 77.0f);
            const float IL = 0.3f * (v + 54.387f);
            const float u = v + 0.01f * (((Ipre - INa) - IK) - IL);
            V[r] = (u != u) ? 0.0f : fminf(fmaxf(u, -100.0f), 100.0f);
        }
        *(float4*)(out + (size_t)k * NN + j0) =
            make_float4(V[0], V[1], V[2], V[3]);
    }
}

extern "C" void kernel_launch(void* const* d_in, const int* in_sizes, int n_in,
                              void* d_out, int out_size, void* d_ws, size_t ws_size,
                              hipStream_t stream)
{
    const float* Iext = (const float*)d_in[0];
    const float* W    = (const float*)d_in[1];
    const float* V0   = (const float*)d_in[2];
    const float* m0   = (const float*)d_in[3];
    const float* h0   = (const float*)d_in[4];
    const float* n0   = (const float*)d_in[5];
    const float* s0   = (const float*)d_in[6];
    const int*   Ty   = (const int*)d_in[7];
    const int*   Tp   = (const int*)d_in[8];
    float* out = (float*)d_out;

    // ws layout: [ctrl 4096 B][cols 6*NN f32][part CH*6*NN f32]
    ull*   ctrl = (ull*)d_ws;
    float* cols = (float*)((char*)d_ws + CTRL_BYTES);
    float* part = cols + (size_t)6 * NN;

    int CH = 0;
    const int tiers[3] = { 128, 64, 8 };
    for (int i = 0; i < 3; ++i) {
        const size_t need = CTRL_BYTES + (size_t)(tiers[i] * 6 + 6) * NN * sizeof(float);
        if (ws_size >= need) { CH = tiers[i]; break; }
    }
    if (CH == 0 && ws_size >= CTRL_BYTES + (size_t)6 * NN * sizeof(float)) CH = 1;

    if (CH >= 1) {
        hipMemsetAsync(ctrl, 0, CTRL_BYTES, stream);   // zero roster/chosen/slots
        if (CH > 1) {
            // 64-thread blocks: grid (NN/256, CH) = 16 x CH
            hipLaunchKernelGGL(col_partial_k, dim3(NN / 256, CH), dim3(64), 0, stream,
                               W, Ty, part, NN / CH);
            hipLaunchKernelGGL(col_reduce_k, dim3(6 * NN / 256), dim3(256), 0, stream,
                               part, cols, CH);
        } else {
            hipLaunchKernelGGL(col_partial_k, dim3(NN / 256, 1), dim3(64), 0, stream,
                               W, Ty, cols, NN);
        }
        hipLaunchKernelGGL(hh_sim_xcd, dim3(GRID_SIM), dim3(NPB), 0, stream,
                           Iext, V0, m0, h0, n0, s0, cols, Tp, ctrl, out);
    } else {
        // pathological tiny workspace: single-block kernel computes cols itself
        hipLaunchKernelGGL(hh_sim_single, dim3(1), dim3(1024), 0, stream,
                           Iext, V0, m0, h0, n0, s0, (const float*)0, Tp, W, Ty, 1, out);
    }
}